// Round 6
// baseline (34.018 us; speedup 1.0000x reference)
//
#include <hip/hip_runtime.h>
#include <hip/hip_bf16.h>

// Sizes (fixed by the reference)
#define N_NODES 1024
#define NUM_MOL 32
#define ATOMS 32
#define SDIM 256
#define VDIM 64
#define EDIM 128
#define NBT 5
#define EDGES_PER_MOL (ATOMS * (ATOMS - 1))        // 992
#define PAIRS_PER_MOL (ATOMS * (ATOMS - 1) / 2)    // 496
#define N_PAIRS (NUM_MOL * PAIRS_PER_MOL)          // 15872

typedef __attribute__((ext_vector_type(8))) short bf16x8;
typedef __attribute__((ext_vector_type(4))) float f32x4;

__device__ __forceinline__ unsigned short f2bf(float x) {
    union { float f; unsigned int u; } v; v.f = x;
    unsigned int r = v.u + 0x7fffu + ((v.u >> 16) & 1u);
    return (unsigned short)(r >> 16);
}

__device__ __forceinline__ bf16x8 pack8(const float4& x0, const float4& x1) {
    bf16x8 r;
    r[0] = (short)f2bf(x0.x); r[1] = (short)f2bf(x0.y);
    r[2] = (short)f2bf(x0.z); r[3] = (short)f2bf(x0.w);
    r[4] = (short)f2bf(x1.x); r[5] = (short)f2bf(x1.y);
    r[6] = (short)f2bf(x1.z); r[7] = (short)f2bf(x1.w);
    return r;
}

// ---------------------------------------------------------------------------
// prep kernel, grid = 257 blocks x 256:
//  bid 0..31   : Wsf  = bf16 B-fragment layout of W_shared
//  bid 32..63  : Wb0f = bf16 B-fragment layout of W_b0[0:256,:]
//  bid 64..191 : sbf  = bf16 A-fragment layout of s
//  bid 192..223: Wf   = 0.5*(W_bond @ W_b0) in bf16 B-fragment layout
//  bid 224..255: coords = center_per_mol(p + v @ W_coords)
//  bid 256     : bcomb = b_bond @ W_b0 + b_b0
// B layout (col-tile nt of 16, k-tile kt of 8): elem(k,n) at
//   [(nt*8+kt)*64 + lane]*8 + e, lane = (n&15)+16*((k>>3)&3), e = k&7.
// A layout (row-block rb of 16, k-tile kt of 8): elem(m,k) at
//   [(rb*8+kt)*64 + lane]*8 + e, lane = (m&15)+16*((k>>3)&3), e = k&7.
// ---------------------------------------------------------------------------
__global__ __launch_bounds__(256) void prep_kernel(
    const float* __restrict__ s, const float* __restrict__ Ws,
    const float* __restrict__ Wb0,
    const float* __restrict__ Wbond, const float* __restrict__ bbond,
    const float* __restrict__ bb0,
    const float* __restrict__ v, const float* __restrict__ p,
    const float* __restrict__ Wc,
    unsigned short* __restrict__ Wsf, unsigned short* __restrict__ Wb0f,
    unsigned short* __restrict__ sbf, unsigned short* __restrict__ Wf,
    float* __restrict__ bcomb, float* __restrict__ coords)
{
    __shared__ __align__(16) float smem[1024 + 16];
    const int t   = threadIdx.x;
    const int bid = blockIdx.x;

    if (bid < 64) {
        // ---- weight -> B-fragment transform (Wsf or Wb0f) ----
        const float* W = (bid < 32) ? Ws : Wb0;
        unsigned short* dst = (bid < 32) ? Wsf : Wb0f;
        const int g    = ((bid & 31) << 8) + t;     // 0..8191 fragment id
        const int lane = g & 63;
        const int kt   = (g >> 6) & 7;              // 8 k-tiles (FIX: was &3)
        const int nt   = g >> 9;                    // 16 col-tiles (FIX: was >>8)
        const int n     = nt * 16 + (lane & 15);
        const int kbase = kt * 32 + (lane >> 4) * 8;
        const float* col = W + (size_t)kbase * SDIM + n;
        bf16x8 r;
#pragma unroll
        for (int e2 = 0; e2 < 8; ++e2) r[e2] = (short)f2bf(col[(size_t)e2 * SDIM]);
        *(bf16x8*)&dst[(size_t)g * 8] = r;

    } else if (bid < 192) {
        // ---- s -> A-fragment transform ----
        const int g    = ((bid - 64) << 8) + t;     // 0..32767
        const int lane = g & 63;
        const int kt   = (g >> 6) & 7;
        const int rb   = g >> 9;
        const int row   = rb * 16 + (lane & 15);
        const int kbase = kt * 32 + (lane >> 4) * 8;
        const float* srow = s + (size_t)row * SDIM + kbase;
        const float4 x0 = *(const float4*)(srow);
        const float4 x1 = *(const float4*)(srow + 4);
        *(bf16x8*)&sbf[(size_t)g * 8] = pack8(x0, x1);

    } else if (bid < 224) {
        // ---- W_comb = 0.5*(W_bond @ W_b0) -> Wf fragments (4 rows/block) ----
        float (*wb)[SDIM] = (float (*)[SDIM])smem;
        const int r0 = (bid - 192) * 4;
        for (int r = 0; r < 4; ++r) wb[r][t] = Wbond[(r0 + r) * SDIM + t];
        __syncthreads();

        float acc[4];
#pragma unroll
        for (int r = 0; r < 4; ++r) acc[r] = 0.f;
        for (int c = 0; c < SDIM; c += 4) {
            const float w0 = Wb0[(c + 0) * SDIM + t];
            const float w1 = Wb0[(c + 1) * SDIM + t];
            const float w2 = Wb0[(c + 2) * SDIM + t];
            const float w3 = Wb0[(c + 3) * SDIM + t];
#pragma unroll
            for (int r = 0; r < 4; ++r) {
                const float4 wv = *(const float4*)&wb[r][c];
                acc[r] += wv.x * w0 + wv.y * w1 + wv.z * w2 + wv.w * w3;
            }
        }
        const int nt = t >> 4;
#pragma unroll
        for (int r = 0; r < 4; ++r) {
            const int k = r0 + r;
            const int kt = k >> 5, g = (k >> 3) & 3, eidx = k & 7;
            const int lane = (t & 15) + 16 * g;
            Wf[((size_t)((nt * 4 + kt) * 64 + lane)) * 8 + eidx] = f2bf(0.5f * acc[r]);
        }

    } else if (bid < 256) {
        // ---- coords ----
        const int mol = bid - 224;
        float* cl   = smem;            // [32][3]
        float* mean = smem + 100;
        if (t < ATOMS * 3) {
            const int a = t / 3, dim = t % 3;
            const int node = mol * ATOMS + a;
            const float* vv = v + (size_t)node * 3 * VDIM + dim * VDIM;
            float acc = 0.f;
#pragma unroll 8
            for (int k = 0; k < VDIM; ++k) acc += vv[k] * Wc[k];
            cl[a * 3 + dim] = p[node * 3 + dim] + acc;
        }
        __syncthreads();
        if (t < 3) {
            float sum = 0.f;
            for (int a = 0; a < ATOMS; ++a) sum += cl[a * 3 + t];
            mean[t] = sum * (1.f / ATOMS);
        }
        __syncthreads();
        if (t < ATOMS * 3) {
            const int a = t / 3, dim = t % 3;
            coords[(mol * ATOMS + a) * 3 + dim] = cl[a * 3 + dim] - mean[dim];
        }
    } else {
        // ---- bcomb ----
        float acc = bb0[t];
#pragma unroll 8
        for (int m = 0; m < SDIM; ++m) acc += bbond[m] * Wb0[m * SDIM + t];
        bcomb[t] = acc;
    }
}

// ---------------------------------------------------------------------------
// node kernel: sp2 = silu(s @ Ws + bs) @ Wb0   (64 blocks x 16 rows)
// All MFMA operands are pre-swizzled fragments -> pure coalesced 16B loads.
// ---------------------------------------------------------------------------
__global__ __launch_bounds__(256) void node_kernel(
    const unsigned short* __restrict__ sbf,
    const unsigned short* __restrict__ Wsf,
    const unsigned short* __restrict__ Wb0f,
    const float* __restrict__ bs,
    float* __restrict__ sp2)
{
    __shared__ __align__(16) unsigned short s2u[16 * 256];   // 8 KB, swizzled
    const int t = threadIdx.x;
    const int w = t >> 6, l = t & 63;
    const int kg = l >> 4, lr = l & 15;
    const int bid = blockIdx.x;
    const int r0 = bid * 16;

    // A1 fragments (coalesced 16B)
    const bf16x8* sfp = (const bf16x8*)sbf;
    bf16x8 a[8];
#pragma unroll
    for (int kt = 0; kt < 8; ++kt) a[kt] = sfp[(bid * 8 + kt) * 64 + l];

    // GEMM1: wave w covers cols 64w..64w+63
    const bf16x8* wsp = (const bf16x8*)Wsf;
    f32x4 acc[4];
#pragma unroll
    for (int q = 0; q < 4; ++q) {
        acc[q][0] = 0.f; acc[q][1] = 0.f; acc[q][2] = 0.f; acc[q][3] = 0.f;
        const int nt = w * 4 + q;
#pragma unroll
        for (int kt = 0; kt < 8; ++kt) {
            const bf16x8 bf = wsp[(nt * 8 + kt) * 64 + l];
            acc[q] = __builtin_amdgcn_mfma_f32_16x16x32_bf16(a[kt], bf, acc[q], 0, 0, 0);
        }
    }

    // bias + silu -> bf16 LDS (XOR-swizzled)
#pragma unroll
    for (int q = 0; q < 4; ++q) {
        const int n = (w * 4 + q) * 16 + lr;
        const float bsv = bs[n];
#pragma unroll
        for (int j = 0; j < 4; ++j) {
            const int row = kg * 4 + j;
            const float x = acc[q][j] + bsv;
            const float sl = x / (1.f + __expf(-x));
            s2u[(row * 256 + n) ^ ((row & 7) << 3)] = f2bf(sl);
        }
    }
    __syncthreads();

    // A2 fragments from LDS
#pragma unroll
    for (int kt = 0; kt < 8; ++kt) {
        const int idx = (lr * 256 + kt * 32 + kg * 8) ^ ((lr & 7) << 3);
        a[kt] = *(const bf16x8*)&s2u[idx];
    }

    // GEMM2 (no bias)
    const bf16x8* wbp = (const bf16x8*)Wb0f;
#pragma unroll
    for (int q = 0; q < 4; ++q) {
        acc[q][0] = 0.f; acc[q][1] = 0.f; acc[q][2] = 0.f; acc[q][3] = 0.f;
        const int nt = w * 4 + q;
#pragma unroll
        for (int kt = 0; kt < 8; ++kt) {
            const bf16x8 bf = wbp[(nt * 8 + kt) * 64 + l];
            acc[q] = __builtin_amdgcn_mfma_f32_16x16x32_bf16(a[kt], bf, acc[q], 0, 0, 0);
        }
    }
#pragma unroll
    for (int q = 0; q < 4; ++q) {
        const int n = (w * 4 + q) * 16 + lr;
#pragma unroll
        for (int j = 0; j < 4; ++j)
            sp2[(size_t)(r0 + kg * 4 + j) * SDIM + n] = acc[q][j];
    }
}

// ---------------------------------------------------------------------------
// Edge kernel: block = 16 pairs, 256 threads = 4 waves, XCD-swizzled bid.
// ---------------------------------------------------------------------------
#define PB 16
__global__ __launch_bounds__(256) void edge_mfma_kernel(
    const float* __restrict__ sp2, const float* __restrict__ coords,
    const float* __restrict__ e, const unsigned short* __restrict__ Wf,
    const float* __restrict__ bcomb, const float* __restrict__ Wb0,
    const float* __restrict__ Wb1, const float* __restrict__ bb1,
    float* __restrict__ out)
{
    __shared__ __align__(16) float spsum[PB][260];           // 16.6 KB
    __shared__ __align__(16) unsigned short esym[PB * EDIM]; // 4 KB, swizzled
    __shared__ float wb1s[SDIM * NBT];                       // 5 KB
    __shared__ float bb1s[8];
    __shared__ int   ksh[PB], krevsh[PB], ish[PB], jsh[PB];
    __shared__ float dsh[PB];

    const int t = threadIdx.x;
    // XCD-bijective swizzle: 992 = 8 * 124 -> each XCD gets 124 consecutive blocks
    const int bid = (blockIdx.x & 7) * 124 + (blockIdx.x >> 3);
    const int P0  = bid * PB;

    for (int idx = t; idx < SDIM * NBT; idx += 256) wb1s[idx] = Wb1[idx];
    if (t < NBT) bb1s[t] = bb1[t];
    if (t < PB) {
        const int P   = P0 + t;
        const int mol = P / PAIRS_PER_MOL;
        const int p   = P - mol * PAIRS_PER_MOL;
        int jj = (int)((63.0f - sqrtf((float)(3969 - 8 * p))) * 0.5f);
        if (jj < 0) jj = 0;
        if (jj > 30) jj = 30;
        while (jj > 0 && (63 * jj - jj * jj) / 2 > p) --jj;
        while (jj < 30 && (63 * (jj + 1) - (jj + 1) * (jj + 1)) / 2 <= p) ++jj;
        const int Ojj = (63 * jj - jj * jj) / 2;
        const int ii  = jj + 1 + (p - Ojj);
        const int q    = jj * 31 + (ii - 1);
        const int qrev = ii * 31 + jj;
        ksh[t]    = mol * EDGES_PER_MOL + q;
        krevsh[t] = mol * EDGES_PER_MOL + qrev;
        const int i = mol * ATOMS + ii, j = mol * ATOMS + jj;
        ish[t] = i; jsh[t] = j;
        const float dx = coords[i * 3 + 0] - coords[j * 3 + 0];
        const float dy = coords[i * 3 + 1] - coords[j * 3 + 1];
        const float dz = coords[i * 3 + 2] - coords[j * 3 + 2];
        dsh[t] = dx * dx + dy * dy + dz * dz;
    }
    __syncthreads();

    // ---- stage e_sym (bf16, swizzled) + spsum fill ----
    {
        const int r  = t >> 4;
        const int c8 = (t & 15) * 8;
        const float* ek  = e + (size_t)ksh[r] * EDIM + c8;
        const float* ekr = e + (size_t)krevsh[r] * EDIM + c8;
        const float4 x0 = *(const float4*)(ek);
        const float4 x1 = *(const float4*)(ek + 4);
        const float4 y0 = *(const float4*)(ekr);
        const float4 y1 = *(const float4*)(ekr + 4);

        const int c0 = (t & 15) * 4;
        const float* ai = sp2 + (size_t)ish[r] * SDIM;
        const float* aj = sp2 + (size_t)jsh[r] * SDIM;
        const float* w2 = Wb0 + (size_t)SDIM * SDIM;   // row 256 of W_b0
        const float d = dsh[r];
#pragma unroll
        for (int i = 0; i < 4; ++i) {
            const int c = c0 + 64 * i;
            const float4 a4 = *(const float4*)(ai + c);
            const float4 b4 = *(const float4*)(aj + c);
            const float4 w4 = *(const float4*)(w2 + c);
            const float4 g4 = *(const float4*)(bcomb + c);
            float4 rv;
            rv.x = a4.x + b4.x + d * w4.x + g4.x;
            rv.y = a4.y + b4.y + d * w4.y + g4.y;
            rv.z = a4.z + b4.z + d * w4.z + g4.z;
            rv.w = a4.w + b4.w + d * w4.w + g4.w;
            *(float4*)&spsum[r][c] = rv;
        }

        float4 sx, sy;
        sx.x = x0.x + y0.x; sx.y = x0.y + y0.y; sx.z = x0.z + y0.z; sx.w = x0.w + y0.w;
        sy.x = x1.x + y1.x; sy.y = x1.y + y1.y; sy.z = x1.z + y1.z; sy.w = x1.w + y1.w;
        const int idx = (r * EDIM + c8) ^ ((r & 7) << 3);
        *(bf16x8*)&esym[idx] = pack8(sx, sy);
    }
    __syncthreads();

    const int w = t >> 6, l = t & 63;
    const int kg = l >> 4, lr = l & 15;

    bf16x8 afrag[4];
#pragma unroll
    for (int kt = 0; kt < 4; ++kt) {
        const int idx = (lr * EDIM + kt * 32 + kg * 8) ^ ((lr & 7) << 3);
        afrag[kt] = *(const bf16x8*)&esym[idx];
    }

    const bf16x8* wfp = (const bf16x8*)Wf;
    f32x4 acc[4];
#pragma unroll
    for (int q = 0; q < 4; ++q) {
        acc[q][0] = 0.f; acc[q][1] = 0.f; acc[q][2] = 0.f; acc[q][3] = 0.f;
        const int nt = w * 4 + q;
        const bf16x8 b0 = wfp[(nt * 4 + 0) * 64 + l];
        const bf16x8 b1 = wfp[(nt * 4 + 1) * 64 + l];
        const bf16x8 b2 = wfp[(nt * 4 + 2) * 64 + l];
        const bf16x8 b3 = wfp[(nt * 4 + 3) * 64 + l];
        acc[q] = __builtin_amdgcn_mfma_f32_16x16x32_bf16(afrag[0], b0, acc[q], 0, 0, 0);
        acc[q] = __builtin_amdgcn_mfma_f32_16x16x32_bf16(afrag[1], b1, acc[q], 0, 0, 0);
        acc[q] = __builtin_amdgcn_mfma_f32_16x16x32_bf16(afrag[2], b2, acc[q], 0, 0, 0);
        acc[q] = __builtin_amdgcn_mfma_f32_16x16x32_bf16(afrag[3], b3, acc[q], 0, 0, 0);
    }

#pragma unroll
    for (int q = 0; q < 4; ++q) {
        const int n = (w * 4 + q) * 16 + lr;
#pragma unroll
        for (int j = 0; j < 4; ++j) {
            const int r = kg * 4 + j;
            const float x = acc[q][j] + spsum[r][n];
            spsum[r][n] = x / (1.f + __expf(-x));
        }
    }
    __syncthreads();

    if (t < PB * NBT * 2) {
        const int task = t >> 1, half = t & 1;
        const int r  = task / NBT;
        const int tt = task - r * NBT;
        float a = half ? 0.f : bb1s[tt];
        const int base = half * 32;
#pragma unroll 4
        for (int cc = 0; cc < 32; ++cc) {
            const int c4 = base + ((cc + task) & 31);
            const int c  = c4 * 4;
            const float4 hv = *(const float4*)&spsum[r][c];
            a += hv.x * wb1s[(c + 0) * NBT + tt] + hv.y * wb1s[(c + 1) * NBT + tt] +
                 hv.z * wb1s[(c + 2) * NBT + tt] + hv.w * wb1s[(c + 3) * NBT + tt];
        }
        a += __shfl_xor(a, 1);
        if (!half) {
            out[(size_t)ksh[r] * NBT + tt]    = a;
            out[(size_t)krevsh[r] * NBT + tt] = a;
        }
    }
}

// ---------------------------------------------------------------------------
extern "C" void kernel_launch(void* const* d_in, const int* in_sizes, int n_in,
                              void* d_out, int out_size, void* d_ws, size_t ws_size,
                              hipStream_t stream)
{
    const float* s        = (const float*)d_in[0];
    const float* v        = (const float*)d_in[1];
    const float* p        = (const float*)d_in[2];
    const float* e        = (const float*)d_in[3];
    const float* W_shared = (const float*)d_in[6];
    const float* b_shared = (const float*)d_in[7];
    const float* W_coords = (const float*)d_in[8];
    const float* W_bond   = (const float*)d_in[9];
    const float* b_bond   = (const float*)d_in[10];
    const float* W_b0     = (const float*)d_in[11];
    const float* b_b0     = (const float*)d_in[12];
    const float* W_b1     = (const float*)d_in[13];
    const float* b_b1     = (const float*)d_in[14];
    float* out = (float*)d_out;

    char* ws = (char*)d_ws;
    float*          sp2    = (float*)(ws + 0);                 // 1 MB
    unsigned short* Wsf    = (unsigned short*)(ws + 1048576);  // 128 KB
    unsigned short* Wb0f   = (unsigned short*)(ws + 1179648);  // 128 KB
    unsigned short* sbf    = (unsigned short*)(ws + 1310720);  // 512 KB
    unsigned short* Wf     = (unsigned short*)(ws + 1835008);  // 64 KB
    float*          bcomb  = (float*)(ws + 1900544);           // 1 KB
    float*          coords = (float*)(ws + 1901568);           // 12 KB

    prep_kernel<<<257, 256, 0, stream>>>(s, W_shared, W_b0, W_bond, b_bond, b_b0,
                                         v, p, W_coords,
                                         Wsf, Wb0f, sbf, Wf, bcomb, coords);
    node_kernel<<<64, 256, 0, stream>>>(sbf, Wsf, Wb0f, b_shared, sp2);
    edge_mfma_kernel<<<N_PAIRS / PB, 256, 0, stream>>>(sp2, coords, e, Wf, bcomb,
                                                       W_b0, W_b1, b_b1, out);
}

// Round 7
// 28.101 us; speedup vs baseline: 1.2106x; 1.2106x over previous
//
#include <hip/hip_runtime.h>
#include <hip/hip_bf16.h>

// Sizes (fixed by the reference)
#define N_NODES 1024
#define NUM_MOL 32
#define ATOMS 32
#define SDIM 256
#define VDIM 64
#define EDIM 128
#define NBT 5
#define EDGES_PER_MOL (ATOMS * (ATOMS - 1))        // 992
#define PAIRS_PER_MOL (ATOMS * (ATOMS - 1) / 2)    // 496
#define N_PAIRS (NUM_MOL * PAIRS_PER_MOL)          // 15872

typedef __attribute__((ext_vector_type(8))) short bf16x8;
typedef __attribute__((ext_vector_type(4))) float f32x4;

__device__ __forceinline__ unsigned short f2bf(float x) {
    union { float f; unsigned int u; } v; v.f = x;
    unsigned int r = v.u + 0x7fffu + ((v.u >> 16) & 1u);
    return (unsigned short)(r >> 16);
}

__device__ __forceinline__ bf16x8 pack8(const float4& x0, const float4& x1) {
    bf16x8 r;
    r[0] = (short)f2bf(x0.x); r[1] = (short)f2bf(x0.y);
    r[2] = (short)f2bf(x0.z); r[3] = (short)f2bf(x0.w);
    r[4] = (short)f2bf(x1.x); r[5] = (short)f2bf(x1.y);
    r[6] = (short)f2bf(x1.z); r[7] = (short)f2bf(x1.w);
    return r;
}

// ---------------------------------------------------------------------------
// prep kernel, grid = 64 blocks x 256: pure B-fragment transforms.
//  bid 0..31 : Wsf  = bf16 B-fragment layout of W_shared
//  bid 32..63: Wb0f = bf16 B-fragment layout of W_b0[0:256,:]
// B layout (col-tile nt of 16, k-tile kt of 8): elem(k,n) at
//   [(nt*8+kt)*64 + lane]*8 + e, lane = (n&15)+16*((k>>3)&3), e = k&7.
// ---------------------------------------------------------------------------
__global__ __launch_bounds__(256) void prep_kernel(
    const float* __restrict__ Ws, const float* __restrict__ Wb0,
    unsigned short* __restrict__ Wsf, unsigned short* __restrict__ Wb0f)
{
    const int t   = threadIdx.x;
    const int bid = blockIdx.x;
    const float* W = (bid < 32) ? Ws : Wb0;
    unsigned short* dst = (bid < 32) ? Wsf : Wb0f;
    const int g    = ((bid & 31) << 8) + t;     // 0..8191 fragment id
    const int lane = g & 63;
    const int kt   = (g >> 6) & 7;              // 8 k-tiles
    const int nt   = g >> 9;                    // 16 col-tiles
    const int n     = nt * 16 + (lane & 15);
    const int kbase = kt * 32 + (lane >> 4) * 8;
    const float* col = W + (size_t)kbase * SDIM + n;
    bf16x8 r;
#pragma unroll
    for (int e2 = 0; e2 < 8; ++e2) r[e2] = (short)f2bf(col[(size_t)e2 * SDIM]);
    *(bf16x8*)&dst[(size_t)g * 8] = r;
}

// ---------------------------------------------------------------------------
// node kernel, grid = 105 blocks x 256:
//  bid 0..63  : sp2 = silu(s @ Ws + bs) @ Wb0   (16 rows/block, MFMA)
//  bid 64..71 : Wf = 0.5*(W_bond @ W_b0) -> bf16 B-frag layout (16 k-rows/blk, MFMA)
//  bid 72..103: coords = center_per_mol(p + v @ W_coords)
//  bid 104    : bcomb = b_bond @ W_b0 + b_b0
// ---------------------------------------------------------------------------
__global__ __launch_bounds__(256) void node_kernel(
    const float* __restrict__ s,
    const unsigned short* __restrict__ Wsf,
    const unsigned short* __restrict__ Wb0f,
    const float* __restrict__ bs,
    const float* __restrict__ Wbond, const float* __restrict__ bbond,
    const float* __restrict__ Wb0, const float* __restrict__ bb0,
    const float* __restrict__ v, const float* __restrict__ p,
    const float* __restrict__ Wc,
    float* __restrict__ sp2, unsigned short* __restrict__ Wf,
    float* __restrict__ coords, float* __restrict__ bcomb)
{
    __shared__ __align__(16) unsigned short s2u[16 * 256];   // 8 KB (node branch)
    const int t = threadIdx.x;
    const int bid = blockIdx.x;
    const int w = t >> 6, l = t & 63;
    const int kg = l >> 4, lr = l & 15;

    if (bid < 64) {
        // ---------------- node GEMM chain ----------------
        const int r0 = bid * 16;

        // A1 fragments straight from s (row-major f32 -> bf16)
        bf16x8 a[8];
        const float* srow = s + (size_t)(r0 + lr) * SDIM + kg * 8;
#pragma unroll
        for (int kt = 0; kt < 8; ++kt) {
            const float4 x0 = *(const float4*)(srow + kt * 32);
            const float4 x1 = *(const float4*)(srow + kt * 32 + 4);
            a[kt] = pack8(x0, x1);
        }

        // GEMM1: wave w covers cols 64w..64w+63
        const bf16x8* wsp = (const bf16x8*)Wsf;
        f32x4 acc[4];
#pragma unroll
        for (int q = 0; q < 4; ++q) {
            acc[q][0] = 0.f; acc[q][1] = 0.f; acc[q][2] = 0.f; acc[q][3] = 0.f;
            const int nt = w * 4 + q;
#pragma unroll
            for (int kt = 0; kt < 8; ++kt) {
                const bf16x8 bf = wsp[(nt * 8 + kt) * 64 + l];
                acc[q] = __builtin_amdgcn_mfma_f32_16x16x32_bf16(a[kt], bf, acc[q], 0, 0, 0);
            }
        }

        // bias + silu -> bf16 LDS (XOR-swizzled)
#pragma unroll
        for (int q = 0; q < 4; ++q) {
            const int n = (w * 4 + q) * 16 + lr;
            const float bsv = bs[n];
#pragma unroll
            for (int j = 0; j < 4; ++j) {
                const int row = kg * 4 + j;
                const float x = acc[q][j] + bsv;
                const float sl = x / (1.f + __expf(-x));
                s2u[(row * 256 + n) ^ ((row & 7) << 3)] = f2bf(sl);
            }
        }
        __syncthreads();

        // A2 fragments from LDS
#pragma unroll
        for (int kt = 0; kt < 8; ++kt) {
            const int idx = (lr * 256 + kt * 32 + kg * 8) ^ ((lr & 7) << 3);
            a[kt] = *(const bf16x8*)&s2u[idx];
        }

        // GEMM2 (no bias)
        const bf16x8* wbp = (const bf16x8*)Wb0f;
#pragma unroll
        for (int q = 0; q < 4; ++q) {
            acc[q][0] = 0.f; acc[q][1] = 0.f; acc[q][2] = 0.f; acc[q][3] = 0.f;
            const int nt = w * 4 + q;
#pragma unroll
            for (int kt = 0; kt < 8; ++kt) {
                const bf16x8 bf = wbp[(nt * 8 + kt) * 64 + l];
                acc[q] = __builtin_amdgcn_mfma_f32_16x16x32_bf16(a[kt], bf, acc[q], 0, 0, 0);
            }
        }
#pragma unroll
        for (int q = 0; q < 4; ++q) {
            const int n = (w * 4 + q) * 16 + lr;
#pragma unroll
            for (int j = 0; j < 4; ++j)
                sp2[(size_t)(r0 + kg * 4 + j) * SDIM + n] = acc[q][j];
        }

    } else if (bid < 72) {
        // ---------------- W_comb via MFMA -> Wf scatter ----------------
        const int r0 = (bid - 64) * 16;          // k-rows of W_comb

        // A fragments straight from Wbond (row-major f32)
        bf16x8 a[8];
        const float* wrow = Wbond + (size_t)(r0 + lr) * SDIM + kg * 8;
#pragma unroll
        for (int kt = 0; kt < 8; ++kt) {
            const float4 x0 = *(const float4*)(wrow + kt * 32);
            const float4 x1 = *(const float4*)(wrow + kt * 32 + 4);
            a[kt] = pack8(x0, x1);
        }

        const bf16x8* wbp = (const bf16x8*)Wb0f;
        f32x4 acc[4];
#pragma unroll
        for (int q = 0; q < 4; ++q) {
            acc[q][0] = 0.f; acc[q][1] = 0.f; acc[q][2] = 0.f; acc[q][3] = 0.f;
            const int nt = w * 4 + q;
#pragma unroll
            for (int kt = 0; kt < 8; ++kt) {
                const bf16x8 bf = wbp[(nt * 8 + kt) * 64 + l];
                acc[q] = __builtin_amdgcn_mfma_f32_16x16x32_bf16(a[kt], bf, acc[q], 0, 0, 0);
            }
        }

        // scatter D -> Wf B-fragment layout with 0.5 scale
        // D elem: krow = r0 + kg*4 + j, n = (w*4+q)*16 + lr
#pragma unroll
        for (int q = 0; q < 4; ++q) {
            const int nt2 = w * 4 + q;
#pragma unroll
            for (int j = 0; j < 4; ++j) {
                const int krow = r0 + kg * 4 + j;
                const int kt2 = krow >> 5, g2 = (krow >> 3) & 3, eidx = krow & 7;
                const int lane2 = lr + 16 * g2;
                Wf[((size_t)((nt2 * 4 + kt2) * 64 + lane2)) * 8 + eidx] =
                    f2bf(0.5f * acc[q][j]);
            }
        }

    } else if (bid < 104) {
        // ---------------- coords ----------------
        const int mol = bid - 72;
        float* cl   = (float*)s2u;       // reuse LDS
        float* mean = (float*)s2u + 100;
        if (t < ATOMS * 3) {
            const int a = t / 3, dim = t % 3;
            const int node = mol * ATOMS + a;
            const float* vv = v + (size_t)node * 3 * VDIM + dim * VDIM;
            float acc = 0.f;
#pragma unroll 8
            for (int k = 0; k < VDIM; ++k) acc += vv[k] * Wc[k];
            cl[a * 3 + dim] = p[node * 3 + dim] + acc;
        }
        __syncthreads();
        if (t < 3) {
            float sum = 0.f;
            for (int a = 0; a < ATOMS; ++a) sum += cl[a * 3 + t];
            mean[t] = sum * (1.f / ATOMS);
        }
        __syncthreads();
        if (t < ATOMS * 3) {
            const int a = t / 3, dim = t % 3;
            coords[(mol * ATOMS + a) * 3 + dim] = cl[a * 3 + dim] - mean[dim];
        }
    } else {
        // ---------------- bcomb ----------------
        float acc = bb0[t];
#pragma unroll 16
        for (int m = 0; m < SDIM; ++m) acc += bbond[m] * Wb0[m * SDIM + t];
        bcomb[t] = acc;
    }
}

// ---------------------------------------------------------------------------
// Edge kernel: block = 16 pairs, 256 threads = 4 waves, XCD-swizzled bid.
// ---------------------------------------------------------------------------
#define PB 16
__global__ __launch_bounds__(256) void edge_mfma_kernel(
    const float* __restrict__ sp2, const float* __restrict__ coords,
    const float* __restrict__ e, const unsigned short* __restrict__ Wf,
    const float* __restrict__ bcomb, const float* __restrict__ Wb0,
    const float* __restrict__ Wb1, const float* __restrict__ bb1,
    float* __restrict__ out)
{
    __shared__ __align__(16) float spsum[PB][260];           // 16.6 KB
    __shared__ __align__(16) unsigned short esym[PB * EDIM]; // 4 KB, swizzled
    __shared__ float wb1s[SDIM * NBT];                       // 5 KB
    __shared__ float bb1s[8];
    __shared__ int   ksh[PB], krevsh[PB], ish[PB], jsh[PB];
    __shared__ float dsh[PB];

    const int t = threadIdx.x;
    // XCD-bijective swizzle: 992 = 8 * 124 -> each XCD gets 124 consecutive blocks
    const int bid = (blockIdx.x & 7) * 124 + (blockIdx.x >> 3);
    const int P0  = bid * PB;

    for (int idx = t; idx < SDIM * NBT; idx += 256) wb1s[idx] = Wb1[idx];
    if (t < NBT) bb1s[t] = bb1[t];
    if (t < PB) {
        const int P   = P0 + t;
        const int mol = P / PAIRS_PER_MOL;
        const int p   = P - mol * PAIRS_PER_MOL;
        int jj = (int)((63.0f - sqrtf((float)(3969 - 8 * p))) * 0.5f);
        if (jj < 0) jj = 0;
        if (jj > 30) jj = 30;
        while (jj > 0 && (63 * jj - jj * jj) / 2 > p) --jj;
        while (jj < 30 && (63 * (jj + 1) - (jj + 1) * (jj + 1)) / 2 <= p) ++jj;
        const int Ojj = (63 * jj - jj * jj) / 2;
        const int ii  = jj + 1 + (p - Ojj);
        const int q    = jj * 31 + (ii - 1);
        const int qrev = ii * 31 + jj;
        ksh[t]    = mol * EDGES_PER_MOL + q;
        krevsh[t] = mol * EDGES_PER_MOL + qrev;
        const int i = mol * ATOMS + ii, j = mol * ATOMS + jj;
        ish[t] = i; jsh[t] = j;
        const float dx = coords[i * 3 + 0] - coords[j * 3 + 0];
        const float dy = coords[i * 3 + 1] - coords[j * 3 + 1];
        const float dz = coords[i * 3 + 2] - coords[j * 3 + 2];
        dsh[t] = dx * dx + dy * dy + dz * dz;
    }
    __syncthreads();

    // ---- stage e_sym (bf16, swizzled) + spsum fill ----
    {
        const int r  = t >> 4;
        const int c8 = (t & 15) * 8;
        const float* ek  = e + (size_t)ksh[r] * EDIM + c8;
        const float* ekr = e + (size_t)krevsh[r] * EDIM + c8;
        const float4 x0 = *(const float4*)(ek);
        const float4 x1 = *(const float4*)(ek + 4);
        const float4 y0 = *(const float4*)(ekr);
        const float4 y1 = *(const float4*)(ekr + 4);

        const int c0 = (t & 15) * 4;
        const float* ai = sp2 + (size_t)ish[r] * SDIM;
        const float* aj = sp2 + (size_t)jsh[r] * SDIM;
        const float* w2 = Wb0 + (size_t)SDIM * SDIM;   // row 256 of W_b0
        const float d = dsh[r];
#pragma unroll
        for (int i = 0; i < 4; ++i) {
            const int c = c0 + 64 * i;
            const float4 a4 = *(const float4*)(ai + c);
            const float4 b4 = *(const float4*)(aj + c);
            const float4 w4 = *(const float4*)(w2 + c);
            const float4 g4 = *(const float4*)(bcomb + c);
            float4 rv;
            rv.x = a4.x + b4.x + d * w4.x + g4.x;
            rv.y = a4.y + b4.y + d * w4.y + g4.y;
            rv.z = a4.z + b4.z + d * w4.z + g4.z;
            rv.w = a4.w + b4.w + d * w4.w + g4.w;
            *(float4*)&spsum[r][c] = rv;
        }

        float4 sx, sy;
        sx.x = x0.x + y0.x; sx.y = x0.y + y0.y; sx.z = x0.z + y0.z; sx.w = x0.w + y0.w;
        sy.x = x1.x + y1.x; sy.y = x1.y + y1.y; sy.z = x1.z + y1.z; sy.w = x1.w + y1.w;
        const int idx = (r * EDIM + c8) ^ ((r & 7) << 3);
        *(bf16x8*)&esym[idx] = pack8(sx, sy);
    }
    __syncthreads();

    const int w = t >> 6, l = t & 63;
    const int kg = l >> 4, lr = l & 15;

    bf16x8 afrag[4];
#pragma unroll
    for (int kt = 0; kt < 4; ++kt) {
        const int idx = (lr * EDIM + kt * 32 + kg * 8) ^ ((lr & 7) << 3);
        afrag[kt] = *(const bf16x8*)&esym[idx];
    }

    const bf16x8* wfp = (const bf16x8*)Wf;
    f32x4 acc[4];
#pragma unroll
    for (int q = 0; q < 4; ++q) {
        acc[q][0] = 0.f; acc[q][1] = 0.f; acc[q][2] = 0.f; acc[q][3] = 0.f;
        const int nt = w * 4 + q;
        const bf16x8 b0 = wfp[(nt * 4 + 0) * 64 + l];
        const bf16x8 b1 = wfp[(nt * 4 + 1) * 64 + l];
        const bf16x8 b2 = wfp[(nt * 4 + 2) * 64 + l];
        const bf16x8 b3 = wfp[(nt * 4 + 3) * 64 + l];
        acc[q] = __builtin_amdgcn_mfma_f32_16x16x32_bf16(afrag[0], b0, acc[q], 0, 0, 0);
        acc[q] = __builtin_amdgcn_mfma_f32_16x16x32_bf16(afrag[1], b1, acc[q], 0, 0, 0);
        acc[q] = __builtin_amdgcn_mfma_f32_16x16x32_bf16(afrag[2], b2, acc[q], 0, 0, 0);
        acc[q] = __builtin_amdgcn_mfma_f32_16x16x32_bf16(afrag[3], b3, acc[q], 0, 0, 0);
    }

#pragma unroll
    for (int q = 0; q < 4; ++q) {
        const int n = (w * 4 + q) * 16 + lr;
#pragma unroll
        for (int j = 0; j < 4; ++j) {
            const int r = kg * 4 + j;
            const float x = acc[q][j] + spsum[r][n];
            spsum[r][n] = x / (1.f + __expf(-x));
        }
    }
    __syncthreads();

    if (t < PB * NBT * 2) {
        const int task = t >> 1, half = t & 1;
        const int r  = task / NBT;
        const int tt = task - r * NBT;
        float a = half ? 0.f : bb1s[tt];
        const int base = half * 32;
#pragma unroll 4
        for (int cc = 0; cc < 32; ++cc) {
            const int c4 = base + ((cc + task) & 31);
            const int c  = c4 * 4;
            const float4 hv = *(const float4*)&spsum[r][c];
            a += hv.x * wb1s[(c + 0) * NBT + tt] + hv.y * wb1s[(c + 1) * NBT + tt] +
                 hv.z * wb1s[(c + 2) * NBT + tt] + hv.w * wb1s[(c + 3) * NBT + tt];
        }
        a += __shfl_xor(a, 1);
        if (!half) {
            out[(size_t)ksh[r] * NBT + tt]    = a;
            out[(size_t)krevsh[r] * NBT + tt] = a;
        }
    }
}

// ---------------------------------------------------------------------------
extern "C" void kernel_launch(void* const* d_in, const int* in_sizes, int n_in,
                              void* d_out, int out_size, void* d_ws, size_t ws_size,
                              hipStream_t stream)
{
    const float* s        = (const float*)d_in[0];
    const float* v        = (const float*)d_in[1];
    const float* p        = (const float*)d_in[2];
    const float* e        = (const float*)d_in[3];
    const float* W_shared = (const float*)d_in[6];
    const float* b_shared = (const float*)d_in[7];
    const float* W_coords = (const float*)d_in[8];
    const float* W_bond   = (const float*)d_in[9];
    const float* b_bond   = (const float*)d_in[10];
    const float* W_b0     = (const float*)d_in[11];
    const float* b_b0     = (const float*)d_in[12];
    const float* W_b1     = (const float*)d_in[13];
    const float* b_b1     = (const float*)d_in[14];
    float* out = (float*)d_out;

    char* ws = (char*)d_ws;
    float*          sp2    = (float*)(ws + 0);                 // 1 MB
    unsigned short* Wsf    = (unsigned short*)(ws + 1048576);  // 128 KB
    unsigned short* Wb0f   = (unsigned short*)(ws + 1179648);  // 128 KB
    unsigned short* Wf     = (unsigned short*)(ws + 1310720);  // 64 KB
    float*          bcomb  = (float*)(ws + 1376256);           // 1 KB
    float*          coords = (float*)(ws + 1377280);           // 12 KB

    prep_kernel<<<64, 256, 0, stream>>>(W_shared, W_b0, Wsf, Wb0f);
    node_kernel<<<105, 256, 0, stream>>>(s, Wsf, Wb0f, b_shared,
                                         W_bond, b_bond, W_b0, b_b0,
                                         v, p, W_coords,
                                         sp2, Wf, coords, bcomb);
    edge_mfma_kernel<<<N_PAIRS / PB, 256, 0, stream>>>(sp2, coords, e, Wf, bcomb,
                                                       W_b0, W_b1, b_b1, out);
}